// Round 16
// baseline (886.116 us; speedup 1.0000x reference)
//
#include <hip/hip_runtime.h>
#include <math.h>

#define HDIM 128
#define NGAUSS 50
#define NLAYER 6
#define TSTR 136   // LDS bf16 tile row stride (shorts); %8==0 keeps ds_read_b128 aligned
#define DINV (1.0f/512.0f)
#define NXCD 8
#define NSTRIPE 512   // edge stripes for the deterministic CSR build

typedef unsigned short ushortT;
typedef __attribute__((ext_vector_type(8))) short bf16x8;
typedef __attribute__((ext_vector_type(4))) float f32x4;

static __device__ __forceinline__ float bf2f(unsigned short u){
  union { unsigned int i; float f; } x; x.i = ((unsigned int)u) << 16; return x.f;
}
static __device__ __forceinline__ float bitsf(unsigned int i){
  union { unsigned int i; float f; } x; x.i = i; return x.f;
}
static __device__ __forceinline__ unsigned short f2bf(float f){
  union { float f; unsigned int i; } x; x.f = f;
  unsigned int i = x.i;
  unsigned int r = (i + 0x7FFFu + ((i >> 16) & 1u)) >> 16;
  return (unsigned short)r;
}
static __device__ __forceinline__ float ssp(float x){
  return fmaxf(x, 0.0f) + __logf(1.0f + __expf(-fabsf(x))) - 0.69314718055994530942f;
}
static __device__ __forceinline__ f32x4 mfma4r(const bf16x8* a, const bf16x8* b){
  f32x4 d = {0.f, 0.f, 0.f, 0.f};
  d = __builtin_amdgcn_mfma_f32_16x16x32_bf16(a[0], b[0], d, 0, 0, 0);
  d = __builtin_amdgcn_mfma_f32_16x16x32_bf16(a[1], b[1], d, 0, 0, 0);
  d = __builtin_amdgcn_mfma_f32_16x16x32_bf16(a[2], b[2], d, 0, 0, 0);
  d = __builtin_amdgcn_mfma_f32_16x16x32_bf16(a[3], b[3], d, 0, 0, 0);
  return d;
}

// ======================= deterministic CSR build =======================
// Dispatch-count-minimized: hist lives in k_setup; k_bscan deleted (scatter
// and place self-scan colTotal); h0 lookup lives in k_colscan.

__global__ __launch_bounds__(256)
void k_colscan(int* __restrict__ hist, int* __restrict__ colTotal,
               const int* __restrict__ z, const ushortT* __restrict__ emb2,
               ushortT* __restrict__ h0, int N, int NB){
  __shared__ int sA[512], sB[512];
  int b = blockIdx.x, tid = threadIdx.x;
  if (b >= NB){
    // h0 lookup section (moved from k_setup; emb2 written by k_setup)
    int base = ((b - NB) * 256 + tid) * 8;
    if (base < N * HDIM){
      int n = base >> 7, f = base & 127;
      *(bf16x8*)(h0 + base) = *(const bf16x8*)(emb2 + z[n] * HDIM + f);
    }
    return;
  }
  sA[tid]       = hist[tid * 512 + b];
  sA[tid + 256] = hist[(tid + 256) * 512 + b];
  __syncthreads();
  int* pa = sA; int* pb = sB;
  for (int off = 1; off < 512; off <<= 1){
    for (int i = tid; i < 512; i += 256)
      pb[i] = pa[i] + (i >= off ? pa[i - off] : 0);
    __syncthreads();
    int* t = pa; pa = pb; pb = t;
  }
  int e0 = (tid == 0) ? 0 : pa[tid - 1];
  int e1 = pa[tid + 255];
  hist[tid * 512 + b]       = e0;
  hist[(tid + 256) * 512 + b] = e1;
  if (tid == 0) colTotal[b] = pa[511];
}

__global__ __launch_bounds__(256)
void k_scatter(const int* __restrict__ erow, const int* __restrict__ ecol,
               const float* __restrict__ pos, const int* __restrict__ hist,
               const int* __restrict__ colTotal, uint2* __restrict__ stg,
               int E, int NB, int shift, int estripe){
  __shared__ int cur[512];
  __shared__ int sA[512], sB[512];
  int tid = threadIdx.x, w = blockIdx.x;
  // self-scan of colTotal -> bucket bases (replaces k_bscan)
  for (int i = tid; i < 512; i += 256) sA[i] = (i < NB) ? colTotal[i] : 0;
  __syncthreads();
  int* pa = sA; int* pb = sB;
  for (int off = 1; off < 512; off <<= 1){
    for (int i = tid; i < 512; i += 256)
      pb[i] = pa[i] + (i >= off ? pa[i - off] : 0);
    __syncthreads();
    int* t = pa; pa = pb; pb = t;
  }
  for (int b = tid; b < NB; b += 256)
    cur[b] = ((b == 0) ? 0 : pa[b - 1]) + hist[w * 512 + b];
  __syncthreads();
  int beg = w * estripe;
  int end = beg + estripe; if (end > E) end = E;
  int mask = (1 << shift) - 1;
  for (int e = beg + tid; e < end; e += 256){
    int r = erow[e], c = ecol[e];
    float dx = pos[r*3+0] - pos[c*3+0];
    float dy = pos[r*3+1] - pos[c*3+1];
    float dz = pos[r*3+2] - pos[c*3+2];
    float d = sqrtf(dx*dx + dy*dy + dz*dz);
    int du = (int)(d * 512.0f + 0.5f);
    if (du > 65535) du = 65535;
    int p = atomicAdd(&cur[r >> shift], 1);   // LDS atomic
    uint2 t;
    t.x = ((unsigned int)c << 16) | (unsigned int)du;
    t.y = (unsigned int)(r & mask);
    stg[p] = t;
  }
}

__global__ __launch_bounds__(256)
void k_place(const uint2* __restrict__ stg, const int* __restrict__ colTotal,
             int* __restrict__ offsets, unsigned int* __restrict__ csr,
             int N, int NB, int shift, int E){
  __shared__ int rc[1024];
  __shared__ int sA[1024], sB[1024];
  int b = blockIdx.x, tid = threadIdx.x;
  int R = 1 << shift;
  int r0 = b << shift;
  // self-scan of colTotal (first 512 slots of sA/sB) -> this bucket's [s,e2)
  for (int i = tid; i < 512; i += 256) sA[i] = (i < NB) ? colTotal[i] : 0;
  __syncthreads();
  int* pa = sA; int* pb = sB;
  for (int off = 1; off < 512; off <<= 1){
    for (int i = tid; i < 512; i += 256)
      pb[i] = pa[i] + (i >= off ? pa[i - off] : 0);
    __syncthreads();
    int* t = pa; pa = pb; pb = t;
  }
  int s  = (b == 0) ? 0 : pa[b - 1];
  int e2 = pa[b];
  __syncthreads();
  for (int i = tid; i < R; i += 256) rc[i] = 0;
  __syncthreads();
  for (int j = s + tid; j < e2; j += 256)
    atomicAdd(&rc[stg[j].y], 1);
  __syncthreads();
  for (int i = tid; i < R; i += 256) sA[i] = rc[i];
  __syncthreads();
  pa = sA; pb = sB;
  for (int off = 1; off < R; off <<= 1){
    for (int i = tid; i < R; i += 256)
      pb[i] = pa[i] + (i >= off ? pa[i - off] : 0);
    __syncthreads();
    int* t = pa; pa = pb; pb = t;
  }
  for (int i = tid; i < R; i += 256){
    int excl = (i == 0) ? 0 : pa[i - 1];
    rc[i] = excl;
    int r = r0 + i;
    if (r < N) offsets[r] = s + excl;
  }
  if (b == NB - 1 && tid == 0) offsets[N] = E;
  __syncthreads();
  for (int j = s + tid; j < e2; j += 256){
    uint2 t = stg[j];
    int slot = s + atomicAdd(&rc[t.y], 1);   // LDS atomic
    csr[slot] = t.x;
  }
}

// ---------------- merged setup (emb2 + transposes + a/c + out-zero + hist) ----
__global__ void k_setup(const float* __restrict__ emb,
                        ushortT* __restrict__ emb2,
                        const float* __restrict__ Wn, ushortT* __restrict__ WnT,
                        const float* __restrict__ Wo, ushortT* __restrict__ WoT,
                        const float* __restrict__ dW, const float* __restrict__ db,
                        const float* __restrict__ We, const float* __restrict__ be,
                        float* __restrict__ a, float* __restrict__ c,
                        const float* __restrict__ W1, ushortT* __restrict__ W1T,
                        const int* __restrict__ erow, int* __restrict__ hist,
                        float* __restrict__ outz,
                        int N, int G, int E, int estripe, int NB, int shift,
                        int B0, int B2, int B4, int B7){
  __shared__ int lh[512];
  int b = blockIdx.x;
  int tid = threadIdx.x;
  if (b < B0){
    // emb2 = emb @ Wn[0]  (100x128 table; replaces k_gemm0 entirely)
    int idx = b * 256 + tid;
    if (idx < 100 * HDIM){
      int i = idx >> 7, f = idx & 127;
      float acc = 0.f;
      #pragma unroll 8
      for (int k = 0; k < HDIM; ++k)
        acc = fmaf(emb[i * HDIM + k], Wn[k * HDIM + f], acc);
      emb2[idx] = f2bf(acc);
    }
    return;
  }
  b -= B0;
  if (b < B2){
    int base = (b * 256 + tid) * 8;
    if (base < NLAYER * HDIM * HDIM){
      int mat = base >> 14, rem = base & 16383;
      int n = rem >> 7, k0 = rem & 127;
      bf16x8 v;
      #pragma unroll
      for (int j = 0; j < 8; ++j)
        v[j] = (short)f2bf(Wn[(mat << 14) + (k0 + j) * HDIM + n]);
      *(bf16x8*)(WnT + base) = v;
    }
    return;
  }
  b -= B2;
  if (b < B2){
    int base = (b * 256 + tid) * 8;
    if (base < NLAYER * HDIM * HDIM){
      int mat = base >> 14, rem = base & 16383;
      int n = rem >> 7, k0 = rem & 127;
      bf16x8 v;
      #pragma unroll
      for (int j = 0; j < 8; ++j)
        v[j] = (short)f2bf(Wo[(mat << 14) + (k0 + j) * HDIM + n]);
      *(bf16x8*)(WoT + base) = v;
    }
    return;
  }
  b -= B2;
  if (b < B4){
    int idx = b * 256 + tid;
    if (idx < NLAYER * HDIM){
      int l = idx >> 7, f = idx & 127;
      float av = 0.f, cv = 0.f;
      for (int g = 0; g < NGAUSS; ++g){
        float we = We[(l * NGAUSS + g) * HDIM + f];
        av += dW[g] * we;
        cv += db[g] * we;
      }
      a[idx] = av;
      c[idx] = cv + be[idx];
    }
    // zero the output accumulator (k_gfinal atomicAdds into it)
    for (int g = b * 256 + tid; g < G; g += B4 * 256) outz[g] = 0.f;
    return;
  }
  b -= B4;
  if (b < B7){
    int base = (b * 256 + tid) * 8;
    if (base < 64 * HDIM){
      int ncol = base >> 7, k0 = base & 127;
      bf16x8 v;
      #pragma unroll
      for (int j = 0; j < 8; ++j)
        v[j] = (short)f2bf(W1[(k0 + j) * 64 + ncol]);
      *(bf16x8*)(W1T + base) = v;
    }
    return;
  }
  b -= B7;
  if (b < NSTRIPE){
    // edge-stripe histogram
    for (int i = tid; i < NB; i += 256) lh[i] = 0;
    __syncthreads();
    int beg = b * estripe;
    int end = beg + estripe; if (end > E) end = E;
    for (int e = beg + tid; e < end; e += 256)
      atomicAdd(&lh[erow[e] >> shift], 1);
    __syncthreads();
    for (int i = tid; i < NB; i += 256) hist[b * 512 + i] = lh[i];
  }
}

// ---------------- edge aggregation: dwordx4 gathers, 2-deep pipeline ----------
// r4 scalar inner loop (verified optimum) + T5 s_setprio around the FMA
// bursts. Mechanism: agg waves are barrier-free and phase-independent (like
// attn, where T5 measured +4-7%; null only on barrier-lockstep GEMM). Raising
// priority during the consume burst returns the wave to gather-issue sooner.
#define AGG_PROC(P, DD) do { \
    unsigned int w_; float lo_, hi_; \
    w_ = (P).x; lo_ = bitsf(w_ << 16); hi_ = bitsf(w_ & 0xFFFF0000u); \
    s1[0] = fmaf(lo_, (DD), s1[0]); s0[0] += lo_; \
    s1[1] = fmaf(hi_, (DD), s1[1]); s0[1] += hi_; \
    w_ = (P).y; lo_ = bitsf(w_ << 16); hi_ = bitsf(w_ & 0xFFFF0000u); \
    s1[2] = fmaf(lo_, (DD), s1[2]); s0[2] += lo_; \
    s1[3] = fmaf(hi_, (DD), s1[3]); s0[3] += hi_; \
    w_ = (P).z; lo_ = bitsf(w_ << 16); hi_ = bitsf(w_ & 0xFFFF0000u); \
    s1[4] = fmaf(lo_, (DD), s1[4]); s0[4] += lo_; \
    s1[5] = fmaf(hi_, (DD), s1[5]); s0[5] += hi_; \
    w_ = (P).w; lo_ = bitsf(w_ << 16); hi_ = bitsf(w_ & 0xFFFF0000u); \
    s1[6] = fmaf(lo_, (DD), s1[6]); s0[6] += lo_; \
    s1[7] = fmaf(hi_, (DD), s1[7]); s0[7] += hi_; \
  } while(0)

#define GATH(Q) (*(const uint4*)(h + ((size_t)((Q) >> 16) << 7) + fl))

__global__ __launch_bounds__(256, 6)
void k_agg2(const ushortT* __restrict__ h, const int* __restrict__ offsets,
            const unsigned int* __restrict__ cd, const float* __restrict__ a,
            const float* __restrict__ c, ushortT* __restrict__ aggHi,
            int N, int segNodes){
  int xcd = blockIdx.x & (NXCD - 1);
  int idx = blockIdx.x >> 3;
  int node = xcd * segNodes + idx * 4 + (threadIdx.x >> 6);
  if (node >= N || node >= (xcd + 1) * segNodes) return;
  int lane = threadIdx.x & 63;
  int quarter = lane >> 4;
  int fl = (lane & 15) * 8;            // 8 features per lane
  int s = offsets[node], e = offsets[node + 1];
  float s0[8] = {0.f,0.f,0.f,0.f,0.f,0.f,0.f,0.f};
  float s1[8] = {0.f,0.f,0.f,0.f,0.f,0.f,0.f,0.f};
  int efull = s + ((e - s) & ~7);
  int L = s;
  if (efull - s >= 16){
    // prologue: issue both batches before any consume (4 gathers in flight)
    unsigned int qA0 = cd[L + quarter],      qA1 = cd[L + 4 + quarter];
    uint4 pA0 = GATH(qA0), pA1 = GATH(qA1);
    unsigned int qB0 = cd[L + 8 + quarter],  qB1 = cd[L + 12 + quarter];
    uint4 pB0 = GATH(qB0), pB1 = GATH(qB1);
    float dA0 = (float)(qA0 & 0xFFFFu) * DINV, dA1 = (float)(qA1 & 0xFFFFu) * DINV;
    float dB0 = (float)(qB0 & 0xFFFFu) * DINV, dB1 = (float)(qB1 & 0xFFFFu) * DINV;
    L += 16;
    for (; L + 16 <= efull; L += 16){
      unsigned int nA0 = cd[L + quarter], nA1 = cd[L + 4 + quarter];
      __builtin_amdgcn_s_setprio(1);
      AGG_PROC(pA0, dA0); AGG_PROC(pA1, dA1);
      __builtin_amdgcn_s_setprio(0);
      pA0 = GATH(nA0); pA1 = GATH(nA1);
      dA0 = (float)(nA0 & 0xFFFFu) * DINV; dA1 = (float)(nA1 & 0xFFFFu) * DINV;
      unsigned int nB0 = cd[L + 8 + quarter], nB1 = cd[L + 12 + quarter];
      __builtin_amdgcn_s_setprio(1);
      AGG_PROC(pB0, dB0); AGG_PROC(pB1, dB1);
      __builtin_amdgcn_s_setprio(0);
      pB0 = GATH(nB0); pB1 = GATH(nB1);
      dB0 = (float)(nB0 & 0xFFFFu) * DINV; dB1 = (float)(nB1 & 0xFFFFu) * DINV;
    }
    // drain
    __builtin_amdgcn_s_setprio(1);
    AGG_PROC(pA0, dA0); AGG_PROC(pA1, dA1);
    AGG_PROC(pB0, dB0); AGG_PROC(pB1, dB1);
    __builtin_amdgcn_s_setprio(0);
  }
  for (; L + 8 <= efull; L += 8){
    unsigned int q0 = cd[L + quarter], q1 = cd[L + 4 + quarter];
    uint4 p0 = GATH(q0), p1 = GATH(q1);
    float d0 = (float)(q0 & 0xFFFFu) * DINV, d1 = (float)(q1 & 0xFFFFu) * DINV;
    __builtin_amdgcn_s_setprio(1);
    AGG_PROC(p0, d0); AGG_PROC(p1, d1);
    __builtin_amdgcn_s_setprio(0);
  }
  for (int j = efull; j < e; j += 4){
    int myj = j + quarter;
    if (myj < e){
      unsigned int q = cd[myj];
      uint4 p = GATH(q);
      float dd = (float)(q & 0xFFFFu) * DINV;
      AGG_PROC(p, dd);
    }
  }
  float4 av0 = *(const float4*)(a + fl);
  float4 av1 = *(const float4*)(a + fl + 4);
  float4 cv0 = *(const float4*)(c + fl);
  float4 cv1 = *(const float4*)(c + fl + 4);
  float r[8];
  r[0] = av0.x * s1[0] + cv0.x * s0[0];
  r[1] = av0.y * s1[1] + cv0.y * s0[1];
  r[2] = av0.z * s1[2] + cv0.z * s0[2];
  r[3] = av0.w * s1[3] + cv0.w * s0[3];
  r[4] = av1.x * s1[4] + cv1.x * s0[4];
  r[5] = av1.y * s1[5] + cv1.y * s0[5];
  r[6] = av1.z * s1[6] + cv1.z * s0[6];
  r[7] = av1.w * s1[7] + cv1.w * s0[7];
  #pragma unroll
  for (int k = 0; k < 8; ++k){
    r[k] += __shfl_down(r[k], 32, 64);
    r[k] += __shfl_down(r[k], 16, 64);
  }
  if (quarter == 0){
    uint4 st;
    st.x = (unsigned int)f2bf(r[0]) | ((unsigned int)f2bf(r[1]) << 16);
    st.y = (unsigned int)f2bf(r[2]) | ((unsigned int)f2bf(r[3]) << 16);
    st.z = (unsigned int)f2bf(r[4]) | ((unsigned int)f2bf(r[5]) << 16);
    st.w = (unsigned int)f2bf(r[6]) | ((unsigned int)f2bf(r[7]) << 16);
    *(uint4*)(aggHi + ((size_t)node << 7) + fl) = st;
  }
}

// ---------------- fused GEMM pair, column-split waves (r9, verified) ----------
__global__ __launch_bounds__(256, 2)
void k_fpair(const ushortT* __restrict__ agg, const ushortT* __restrict__ WoT,
             const float* __restrict__ bo, const ushortT* __restrict__ WnT,
             ushortT* __restrict__ outH, int N, int segTiles){
  __shared__ ushortT vt[2][32 * TSTR];
  int tid = threadIdx.x;
  int wave = tid >> 6, lane = tid & 63;
  int pairI = wave >> 1, half = wave & 1;
  int m = lane & 15, quad = lane >> 4;
  int ntiles = (N + 15) >> 4;
  int xcd = blockIdx.x & (NXCD - 1);
  int idx = blockIdx.x >> 3;
  int wjIdx = idx * 2 + pairI;
  int segWJ = segTiles >> 1;
  int t0 = xcd * segTiles + wjIdx * 2;
  bool act = (wjIdx < segWJ) && (t0 < ntiles);
  ushortT* vw = vt[pairI];

  bf16x8 av[2][4];
  if (act){
    #pragma unroll
    for (int rt = 0; rt < 2; ++rt){
      int row = (t0 + rt) * 16 + m; if (row >= N) row = N - 1;
      #pragma unroll
      for (int kk = 0; kk < 4; ++kk)
        av[rt][kk] = *(const bf16x8*)(agg + ((size_t)row << 7) + kk*32 + quad*8);
    }
    #pragma unroll
    for (int cti = 0; cti < 4; ++cti){
      int ncol = (half * 4 + cti) * 16 + m;
      const ushortT* bp = WoT + ((size_t)ncol << 7) + quad*8;
      bf16x8 bb[4];
      #pragma unroll
      for (int kk = 0; kk < 4; ++kk) bb[kk] = *(const bf16x8*)(bp + kk*32);
      float bbias = bo[ncol];
      #pragma unroll
      for (int rt = 0; rt < 2; ++rt){
        f32x4 d = mfma4r(av[rt], bb);
        #pragma unroll
        for (int r = 0; r < 4; ++r)
          vw[(rt*16 + quad*4 + r) * TSTR + ncol] = f2bf(ssp(d[r] + bbias));
      }
    }
  }
  __syncthreads();
  if (act){
    bf16x8 a2[2][4];
    #pragma unroll
    for (int rt = 0; rt < 2; ++rt){
      #pragma unroll
      for (int kk = 0; kk < 4; ++kk)
        a2[rt][kk] = *(const bf16x8*)(&vw[(rt*16 + m) * TSTR + kk*32 + quad*8]);
    }
    #pragma unroll
    for (int cti = 0; cti < 4; ++cti){
      int ncol = (half * 4 + cti) * 16 + m;
      const ushortT* bp = WnT + ((size_t)ncol << 7) + quad*8;
      bf16x8 bb[4];
      #pragma unroll
      for (int kk = 0; kk < 4; ++kk) bb[kk] = *(const bf16x8*)(bp + kk*32);
      #pragma unroll
      for (int rt = 0; rt < 2; ++rt){
        f32x4 d = mfma4r(a2[rt], bb);
        #pragma unroll
        for (int r = 0; r < 4; ++r){
          int orow = (t0 + rt) * 16 + quad*4 + r;
          if (orow < N) outH[((size_t)orow << 7) + ncol] = f2bf(d[r]);
        }
      }
    }
  }
}

// ------ last layer: column-split + fused group-sum, run-compacted atomics -----
// (r15 verified: segmented shfl-scan over sorted batch, run-tail lanes only
// -> ~3K atomics, contention gone.)
__global__ __launch_bounds__(256, 2)
void k_gfinal(const ushortT* __restrict__ agg, const ushortT* __restrict__ WoT,
              const float* __restrict__ bo, const ushortT* __restrict__ W1T,
              const float* __restrict__ b1, const float* __restrict__ W2,
              const float* __restrict__ b2, const int* __restrict__ batch,
              float* __restrict__ out, int N, int segTiles){
  __shared__ ushortT vt[2][32 * TSTR];
  __shared__ float part[2][2][32];
  int tid = threadIdx.x;
  int wave = tid >> 6, lane = tid & 63;
  int pairI = wave >> 1, half = wave & 1;
  int m = lane & 15, quad = lane >> 4;
  int ntiles = (N + 15) >> 4;
  int xcd = blockIdx.x & (NXCD - 1);
  int idx = blockIdx.x >> 3;
  int wjIdx = idx * 2 + pairI;
  int segWJ = segTiles >> 1;
  int t0 = xcd * segTiles + wjIdx * 2;
  bool act = (wjIdx < segWJ) && (t0 < ntiles);
  ushortT* vw = vt[pairI];

  if (act){
    bf16x8 av[2][4];
    #pragma unroll
    for (int rt = 0; rt < 2; ++rt){
      int row = (t0 + rt) * 16 + m; if (row >= N) row = N - 1;
      #pragma unroll
      for (int kk = 0; kk < 4; ++kk)
        av[rt][kk] = *(const bf16x8*)(agg + ((size_t)row << 7) + kk*32 + quad*8);
    }
    #pragma unroll
    for (int cti = 0; cti < 4; ++cti){
      int ncol = (half * 4 + cti) * 16 + m;
      const ushortT* bp = WoT + ((size_t)ncol << 7) + quad*8;
      bf16x8 bb[4];
      #pragma unroll
      for (int kk = 0; kk < 4; ++kk) bb[kk] = *(const bf16x8*)(bp + kk*32);
      float bbias = bo[ncol];
      #pragma unroll
      for (int rt = 0; rt < 2; ++rt){
        f32x4 d = mfma4r(av[rt], bb);
        #pragma unroll
        for (int r = 0; r < 4; ++r)
          vw[(rt*16 + quad*4 + r) * TSTR + ncol] = f2bf(ssp(d[r] + bbias));
      }
    }
  }
  __syncthreads();
  if (act){
    bf16x8 a2[2][4];
    #pragma unroll
    for (int rt = 0; rt < 2; ++rt){
      #pragma unroll
      for (int kk = 0; kk < 4; ++kk)
        a2[rt][kk] = *(const bf16x8*)(&vw[(rt*16 + m) * TSTR + kk*32 + quad*8]);
    }
    float acc[2][4] = {{0.f,0.f,0.f,0.f},{0.f,0.f,0.f,0.f}};
    #pragma unroll
    for (int cti = 0; cti < 2; ++cti){
      int ncol = (half * 2 + cti) * 16 + m;       // W1T: 64 cols total
      const ushortT* bp = W1T + ((size_t)ncol << 7) + quad*8;
      bf16x8 bb[4];
      #pragma unroll
      for (int kk = 0; kk < 4; ++kk) bb[kk] = *(const bf16x8*)(bp + kk*32);
      float bb1 = b1[ncol];
      float w2  = W2[ncol];
      #pragma unroll
      for (int rt = 0; rt < 2; ++rt){
        f32x4 d = mfma4r(a2[rt], bb);
        #pragma unroll
        for (int r = 0; r < 4; ++r)
          acc[rt][r] += ssp(d[r] + bb1) * w2;
      }
    }
    #pragma unroll
    for (int rt = 0; rt < 2; ++rt){
      #pragma unroll
      for (int r = 0; r < 4; ++r){
        float v = acc[rt][r];
        v += __shfl_xor(v, 1, 64);
        v += __shfl_xor(v, 2, 64);
        v += __shfl_xor(v, 4, 64);
        v += __shfl_xor(v, 8, 64);
        if (m == 0) part[pairI][half][rt*16 + quad*4 + r] = v;
      }
    }
  }
  __syncthreads();
  if (tid < 64){
    int p = tid >> 5, row = tid & 31;
    int wj = idx * 2 + p;
    int tt = xcd * segTiles + wj * 2;
    bool valid = (wj < segWJ) && (tt < ntiles);
    int orow = valid ? (tt * 16 + row) : 0;
    valid = valid && (orow < N);
    float v = 0.f; int g = -1;
    if (valid){
      v = part[p][0][row] + part[p][1][row] + b2[0];
      g = batch[orow];
    }
    // segmented inclusive scan over each 32-lane half (sorted batch => runs)
    #pragma unroll
    for (int off = 1; off < 32; off <<= 1){
      int src = tid - off; if (src < 0) src = 0;
      float ov = __shfl(v, src, 64);
      int   og = __shfl(g, src, 64);
      if (row >= off && og == g) v += ov;
    }
    if (valid){
      bool tail = (row == 31) || (orow == N - 1);
      if (!tail) tail = (batch[orow + 1] != g);
      if (tail) atomicAdd(&out[g], v);   // only run tails hit memory
    }
  }
}

extern "C" void kernel_launch(void* const* d_in, const int* in_sizes, int n_in,
                              void* d_out, int out_size, void* d_ws, size_t ws_size,
                              hipStream_t stream){
  const int N = in_sizes[0];
  const int E = in_sizes[3] / 2;
  const int G = out_size;

  const int*   z     = (const int*)d_in[0];
  const float* pos   = (const float*)d_in[1];
  const int*   batch = (const int*)d_in[2];
  const int*   eidx  = (const int*)d_in[3];
  const int*   erow  = eidx;
  const int*   ecol  = eidx + E;
  const float* emb   = (const float*)d_in[4];
  const float* dW    = (const float*)d_in[5];
  const float* db    = (const float*)d_in[6];
  const float* Wn    = (const float*)d_in[7];
  const float* We    = (const float*)d_in[8];
  const float* be    = (const float*)d_in[9];
  const float* Wo    = (const float*)d_in[10];
  const float* bo    = (const float*)d_in[11];
  const float* W1    = (const float*)d_in[12];
  const float* b1    = (const float*)d_in[13];
  const float* W2    = (const float*)d_in[14];
  const float* b2    = (const float*)d_in[15];

  char* ws = (char*)d_ws;
  size_t off = 0;
  auto alloc = [&](size_t bytes) -> char* {
    char* p = ws + off;
    off = (off + bytes + 255) & ~(size_t)255;
    return p;
  };
  size_t hbytes = (size_t)N * HDIM * 2;
  size_t stgbytes = (size_t)E * 8;
  int*          offsets  = (int*)         alloc((size_t)(N + 1) * 4);
  unsigned int* csr      = (unsigned int*)alloc((size_t)E * 4);
  ushortT*      h0       = (ushortT*)     alloc(hbytes);
  ushortT*      h1       = (ushortT*)     alloc(hbytes);    // aliased by hist during build
  ushortT*      agghi    = (ushortT*)     alloc(hbytes);
  ushortT*      stgbuf   = (ushortT*)     alloc(stgbytes);  // CSR staging records
  ushortT*      emb2     = (ushortT*)     alloc((size_t)100 * HDIM * 2);
  ushortT*      WnT      = (ushortT*)     alloc((size_t)NLAYER * HDIM * HDIM * 2);
  ushortT*      WoT      = (ushortT*)     alloc((size_t)NLAYER * HDIM * HDIM * 2);
  ushortT*      W1T      = (ushortT*)     alloc((size_t)64 * HDIM * 2);
  float*        a        = (float*)       alloc((size_t)NLAYER * HDIM * 4);
  float*        c        = (float*)       alloc((size_t)NLAYER * HDIM * 4);

  int*   hist       = (int*)h1;                 // NSTRIPE*512 ints = 1 MB
  int*   colTotal   = hist + NSTRIPE * 512;     // 512 ints
  uint2* stg        = (uint2*)stgbuf;           // E * 8 B

  int shift = 7;
  while ((((N - 1) >> shift) + 1) > 512) ++shift;
  int NB = ((N - 1) >> shift) + 1;
  int estripe = (E + NSTRIPE - 1) / NSTRIPE;

  int B0 = (100 * HDIM + 255) / 256;
  int B2 = (NLAYER * HDIM * HDIM / 8 + 255) / 256;
  int B4 = (NLAYER * HDIM + 255) / 256;
  int B7 = (64 * HDIM / 8 + 255) / 256;
  int B1h = (N * HDIM / 8 + 255) / 256;

  k_setup<<<B0 + 2*B2 + B4 + B7 + NSTRIPE, 256, 0, stream>>>(
      emb, emb2, Wn, WnT, Wo, WoT,
      dW, db, We, be, a, c, W1, W1T,
      erow, hist, (float*)d_out,
      N, G, E, estripe, NB, shift, B0, B2, B4, B7);

  k_colscan<<<NB + B1h, 256, 0, stream>>>(hist, colTotal, z, emb2, h0, N, NB);
  k_scatter<<<NSTRIPE, 256, 0, stream>>>(erow, ecol, pos, hist, colTotal,
                                         stg, E, NB, shift, estripe);
  k_place  <<<NB,      256, 0, stream>>>(stg, colTotal, offsets, csr, N, NB, shift, E);

  int ntiles = (N + 15) >> 4;
  int segTiles = (((ntiles + NXCD - 1) / NXCD) + 1) & ~1;   // even tiles/XCD
  int segNodes = segTiles * 16;
  int segWJ = segTiles >> 1;
  int aggGrid  = NXCD * ((segNodes + 3) / 4);
  int gGrid    = NXCD * ((segWJ + 1) / 2);

  for (int l = 0; l < NLAYER; ++l){
    size_t wo = (size_t)l * HDIM * HDIM;
    const ushortT* hin  = (l & 1) ? h1 : h0;
    ushortT*       hout = (l & 1) ? h0 : h1;
    k_agg2<<<aggGrid, 256, 0, stream>>>(hin, offsets, csr,
                                        a + l * HDIM, c + l * HDIM, agghi, N, segNodes);
    if (l < NLAYER - 1){
      size_t wn = (size_t)(l + 1) * HDIM * HDIM;
      k_fpair<<<gGrid, 256, 0, stream>>>(agghi, WoT + wo, bo + (size_t)l * HDIM,
                                         WnT + wn, hout, N, segTiles);
    } else {
      k_gfinal<<<gGrid, 256, 0, stream>>>(agghi, WoT + wo, bo + (size_t)l * HDIM,
                                          W1T, b1, W2, b2, batch,
                                          (float*)d_out, N, segTiles);
    }
  }
}

// Round 17
// 556.508 us; speedup vs baseline: 1.5923x; 1.5923x over previous
//
#include <hip/hip_runtime.h>
#include <math.h>

#define HDIM 128
#define NGAUSS 50
#define NLAYER 6
#define TSTR 136   // LDS bf16 tile row stride (shorts); %8==0 keeps ds_read_b128 aligned
#define DINV (1.0f/512.0f)
#define NXCD 8
#define NSTRIPE 512   // edge stripes for the deterministic CSR build

typedef unsigned short ushortT;
typedef __attribute__((ext_vector_type(8))) short bf16x8;
typedef __attribute__((ext_vector_type(4))) float f32x4;

static __device__ __forceinline__ float bf2f(unsigned short u){
  union { unsigned int i; float f; } x; x.i = ((unsigned int)u) << 16; return x.f;
}
static __device__ __forceinline__ float bitsf(unsigned int i){
  union { unsigned int i; float f; } x; x.i = i; return x.f;
}
static __device__ __forceinline__ unsigned short f2bf(float f){
  union { float f; unsigned int i; } x; x.f = f;
  unsigned int i = x.i;
  unsigned int r = (i + 0x7FFFu + ((i >> 16) & 1u)) >> 16;
  return (unsigned short)r;
}
static __device__ __forceinline__ float ssp(float x){
  return fmaxf(x, 0.0f) + __logf(1.0f + __expf(-fabsf(x))) - 0.69314718055994530942f;
}
static __device__ __forceinline__ f32x4 mfma4r(const bf16x8* a, const bf16x8* b){
  f32x4 d = {0.f, 0.f, 0.f, 0.f};
  d = __builtin_amdgcn_mfma_f32_16x16x32_bf16(a[0], b[0], d, 0, 0, 0);
  d = __builtin_amdgcn_mfma_f32_16x16x32_bf16(a[1], b[1], d, 0, 0, 0);
  d = __builtin_amdgcn_mfma_f32_16x16x32_bf16(a[2], b[2], d, 0, 0, 0);
  d = __builtin_amdgcn_mfma_f32_16x16x32_bf16(a[3], b[3], d, 0, 0, 0);
  return d;
}

// ======================= deterministic CSR build =======================
// Dispatch-count-minimized: hist lives in k_setup; k_bscan deleted (scatter
// and place self-scan colTotal); h0 lookup lives in k_colscan.

__global__ __launch_bounds__(256)
void k_colscan(int* __restrict__ hist, int* __restrict__ colTotal,
               const int* __restrict__ z, const ushortT* __restrict__ emb2,
               ushortT* __restrict__ h0, int N, int NB){
  __shared__ int sA[512], sB[512];
  int b = blockIdx.x, tid = threadIdx.x;
  if (b >= NB){
    // h0 lookup section (moved from k_setup; emb2 written by k_setup)
    int base = ((b - NB) * 256 + tid) * 8;
    if (base < N * HDIM){
      int n = base >> 7, f = base & 127;
      *(bf16x8*)(h0 + base) = *(const bf16x8*)(emb2 + z[n] * HDIM + f);
    }
    return;
  }
  sA[tid]       = hist[tid * 512 + b];
  sA[tid + 256] = hist[(tid + 256) * 512 + b];
  __syncthreads();
  int* pa = sA; int* pb = sB;
  for (int off = 1; off < 512; off <<= 1){
    for (int i = tid; i < 512; i += 256)
      pb[i] = pa[i] + (i >= off ? pa[i - off] : 0);
    __syncthreads();
    int* t = pa; pa = pb; pb = t;
  }
  int e0 = (tid == 0) ? 0 : pa[tid - 1];
  int e1 = pa[tid + 255];
  hist[tid * 512 + b]       = e0;
  hist[(tid + 256) * 512 + b] = e1;
  if (tid == 0) colTotal[b] = pa[511];
}

__global__ __launch_bounds__(256)
void k_scatter(const int* __restrict__ erow, const int* __restrict__ ecol,
               const float* __restrict__ pos, const int* __restrict__ hist,
               const int* __restrict__ colTotal, uint2* __restrict__ stg,
               int E, int NB, int shift, int estripe){
  __shared__ int cur[512];
  __shared__ int sA[512], sB[512];
  int tid = threadIdx.x, w = blockIdx.x;
  // self-scan of colTotal -> bucket bases (replaces k_bscan)
  for (int i = tid; i < 512; i += 256) sA[i] = (i < NB) ? colTotal[i] : 0;
  __syncthreads();
  int* pa = sA; int* pb = sB;
  for (int off = 1; off < 512; off <<= 1){
    for (int i = tid; i < 512; i += 256)
      pb[i] = pa[i] + (i >= off ? pa[i - off] : 0);
    __syncthreads();
    int* t = pa; pa = pb; pb = t;
  }
  for (int b = tid; b < NB; b += 256)
    cur[b] = ((b == 0) ? 0 : pa[b - 1]) + hist[w * 512 + b];
  __syncthreads();
  int beg = w * estripe;
  int end = beg + estripe; if (end > E) end = E;
  int mask = (1 << shift) - 1;
  for (int e = beg + tid; e < end; e += 256){
    int r = erow[e], c = ecol[e];
    float dx = pos[r*3+0] - pos[c*3+0];
    float dy = pos[r*3+1] - pos[c*3+1];
    float dz = pos[r*3+2] - pos[c*3+2];
    float d = sqrtf(dx*dx + dy*dy + dz*dz);
    int du = (int)(d * 512.0f + 0.5f);
    if (du > 65535) du = 65535;
    int p = atomicAdd(&cur[r >> shift], 1);   // LDS atomic
    uint2 t;
    t.x = ((unsigned int)c << 16) | (unsigned int)du;
    t.y = (unsigned int)(r & mask);
    stg[p] = t;
  }
}

__global__ __launch_bounds__(256)
void k_place(const uint2* __restrict__ stg, const int* __restrict__ colTotal,
             int* __restrict__ offsets, unsigned int* __restrict__ csr,
             int N, int NB, int shift, int E){
  __shared__ int rc[1024];
  __shared__ int sA[1024], sB[1024];
  int b = blockIdx.x, tid = threadIdx.x;
  int R = 1 << shift;
  int r0 = b << shift;
  // self-scan of colTotal (first 512 slots of sA/sB) -> this bucket's [s,e2)
  for (int i = tid; i < 512; i += 256) sA[i] = (i < NB) ? colTotal[i] : 0;
  __syncthreads();
  int* pa = sA; int* pb = sB;
  for (int off = 1; off < 512; off <<= 1){
    for (int i = tid; i < 512; i += 256)
      pb[i] = pa[i] + (i >= off ? pa[i - off] : 0);
    __syncthreads();
    int* t = pa; pa = pb; pb = t;
  }
  int s  = (b == 0) ? 0 : pa[b - 1];
  int e2 = pa[b];
  __syncthreads();
  for (int i = tid; i < R; i += 256) rc[i] = 0;
  __syncthreads();
  for (int j = s + tid; j < e2; j += 256)
    atomicAdd(&rc[stg[j].y], 1);
  __syncthreads();
  for (int i = tid; i < R; i += 256) sA[i] = rc[i];
  __syncthreads();
  pa = sA; pb = sB;
  for (int off = 1; off < R; off <<= 1){
    for (int i = tid; i < R; i += 256)
      pb[i] = pa[i] + (i >= off ? pa[i - off] : 0);
    __syncthreads();
    int* t = pa; pa = pb; pb = t;
  }
  for (int i = tid; i < R; i += 256){
    int excl = (i == 0) ? 0 : pa[i - 1];
    rc[i] = excl;
    int r = r0 + i;
    if (r < N) offsets[r] = s + excl;
  }
  if (b == NB - 1 && tid == 0) offsets[N] = E;
  __syncthreads();
  for (int j = s + tid; j < e2; j += 256){
    uint2 t = stg[j];
    int slot = s + atomicAdd(&rc[t.y], 1);   // LDS atomic
    csr[slot] = t.x;
  }
}

// ---------------- merged setup (emb2 + transposes + a/c + out-zero + hist) ----
__global__ void k_setup(const float* __restrict__ emb,
                        ushortT* __restrict__ emb2,
                        const float* __restrict__ Wn, ushortT* __restrict__ WnT,
                        const float* __restrict__ Wo, ushortT* __restrict__ WoT,
                        const float* __restrict__ dW, const float* __restrict__ db,
                        const float* __restrict__ We, const float* __restrict__ be,
                        float* __restrict__ a, float* __restrict__ c,
                        const float* __restrict__ W1, ushortT* __restrict__ W1T,
                        const int* __restrict__ erow, int* __restrict__ hist,
                        float* __restrict__ outz,
                        int N, int G, int E, int estripe, int NB, int shift,
                        int B0, int B2, int B4, int B7){
  __shared__ int lh[512];
  int b = blockIdx.x;
  int tid = threadIdx.x;
  if (b < B0){
    // emb2 = emb @ Wn[0]  (100x128 table; replaces k_gemm0 entirely)
    int idx = b * 256 + tid;
    if (idx < 100 * HDIM){
      int i = idx >> 7, f = idx & 127;
      float acc = 0.f;
      #pragma unroll 8
      for (int k = 0; k < HDIM; ++k)
        acc = fmaf(emb[i * HDIM + k], Wn[k * HDIM + f], acc);
      emb2[idx] = f2bf(acc);
    }
    return;
  }
  b -= B0;
  if (b < B2){
    int base = (b * 256 + tid) * 8;
    if (base < NLAYER * HDIM * HDIM){
      int mat = base >> 14, rem = base & 16383;
      int n = rem >> 7, k0 = rem & 127;
      bf16x8 v;
      #pragma unroll
      for (int j = 0; j < 8; ++j)
        v[j] = (short)f2bf(Wn[(mat << 14) + (k0 + j) * HDIM + n]);
      *(bf16x8*)(WnT + base) = v;
    }
    return;
  }
  b -= B2;
  if (b < B2){
    int base = (b * 256 + tid) * 8;
    if (base < NLAYER * HDIM * HDIM){
      int mat = base >> 14, rem = base & 16383;
      int n = rem >> 7, k0 = rem & 127;
      bf16x8 v;
      #pragma unroll
      for (int j = 0; j < 8; ++j)
        v[j] = (short)f2bf(Wo[(mat << 14) + (k0 + j) * HDIM + n]);
      *(bf16x8*)(WoT + base) = v;
    }
    return;
  }
  b -= B2;
  if (b < B4){
    int idx = b * 256 + tid;
    if (idx < NLAYER * HDIM){
      int l = idx >> 7, f = idx & 127;
      float av = 0.f, cv = 0.f;
      for (int g = 0; g < NGAUSS; ++g){
        float we = We[(l * NGAUSS + g) * HDIM + f];
        av += dW[g] * we;
        cv += db[g] * we;
      }
      a[idx] = av;
      c[idx] = cv + be[idx];
    }
    // zero the output accumulator (k_gfinal atomicAdds into it)
    for (int g = b * 256 + tid; g < G; g += B4 * 256) outz[g] = 0.f;
    return;
  }
  b -= B4;
  if (b < B7){
    int base = (b * 256 + tid) * 8;
    if (base < 64 * HDIM){
      int ncol = base >> 7, k0 = base & 127;
      bf16x8 v;
      #pragma unroll
      for (int j = 0; j < 8; ++j)
        v[j] = (short)f2bf(W1[(k0 + j) * 64 + ncol]);
      *(bf16x8*)(W1T + base) = v;
    }
    return;
  }
  b -= B7;
  if (b < NSTRIPE){
    // edge-stripe histogram
    for (int i = tid; i < NB; i += 256) lh[i] = 0;
    __syncthreads();
    int beg = b * estripe;
    int end = beg + estripe; if (end > E) end = E;
    for (int e = beg + tid; e < end; e += 256)
      atomicAdd(&lh[erow[e] >> shift], 1);
    __syncthreads();
    for (int i = tid; i < NB; i += 256) hist[b * 512 + i] = lh[i];
  }
}

// ---------------- edge aggregation: dwordx4 gathers, 2-deep pipeline ----------
// r4/r15 scalar version — the verified optimum. Closed perturbation ledger:
// depth 1/2/3 = 56.5/48.8/50.9us; nt-loads +8.6MB fetch; packed-f32 spills
// (arrays r5, named f32x2 r10); s_setprio in-loop spills catastrophically
// (r16: VGPR 40, WRITE 12.5->209MB, 2.2x slower — intrinsic blocks the
// scheduler's GATH/FMA interleave). Scalar named floats, depth 2, VGPR 32.
#define AGG_PROC(P, DD) do { \
    unsigned int w_; float lo_, hi_; \
    w_ = (P).x; lo_ = bitsf(w_ << 16); hi_ = bitsf(w_ & 0xFFFF0000u); \
    s1[0] = fmaf(lo_, (DD), s1[0]); s0[0] += lo_; \
    s1[1] = fmaf(hi_, (DD), s1[1]); s0[1] += hi_; \
    w_ = (P).y; lo_ = bitsf(w_ << 16); hi_ = bitsf(w_ & 0xFFFF0000u); \
    s1[2] = fmaf(lo_, (DD), s1[2]); s0[2] += lo_; \
    s1[3] = fmaf(hi_, (DD), s1[3]); s0[3] += hi_; \
    w_ = (P).z; lo_ = bitsf(w_ << 16); hi_ = bitsf(w_ & 0xFFFF0000u); \
    s1[4] = fmaf(lo_, (DD), s1[4]); s0[4] += lo_; \
    s1[5] = fmaf(hi_, (DD), s1[5]); s0[5] += hi_; \
    w_ = (P).w; lo_ = bitsf(w_ << 16); hi_ = bitsf(w_ & 0xFFFF0000u); \
    s1[6] = fmaf(lo_, (DD), s1[6]); s0[6] += lo_; \
    s1[7] = fmaf(hi_, (DD), s1[7]); s0[7] += hi_; \
  } while(0)

#define GATH(Q) (*(const uint4*)(h + ((size_t)((Q) >> 16) << 7) + fl))

__global__ __launch_bounds__(256, 6)
void k_agg2(const ushortT* __restrict__ h, const int* __restrict__ offsets,
            const unsigned int* __restrict__ cd, const float* __restrict__ a,
            const float* __restrict__ c, ushortT* __restrict__ aggHi,
            int N, int segNodes){
  int xcd = blockIdx.x & (NXCD - 1);
  int idx = blockIdx.x >> 3;
  int node = xcd * segNodes + idx * 4 + (threadIdx.x >> 6);
  if (node >= N || node >= (xcd + 1) * segNodes) return;
  int lane = threadIdx.x & 63;
  int quarter = lane >> 4;
  int fl = (lane & 15) * 8;            // 8 features per lane
  int s = offsets[node], e = offsets[node + 1];
  float s0[8] = {0.f,0.f,0.f,0.f,0.f,0.f,0.f,0.f};
  float s1[8] = {0.f,0.f,0.f,0.f,0.f,0.f,0.f,0.f};
  int efull = s + ((e - s) & ~7);
  int L = s;
  if (efull - s >= 16){
    // prologue: issue both batches before any consume (4 gathers in flight)
    unsigned int qA0 = cd[L + quarter],      qA1 = cd[L + 4 + quarter];
    uint4 pA0 = GATH(qA0), pA1 = GATH(qA1);
    unsigned int qB0 = cd[L + 8 + quarter],  qB1 = cd[L + 12 + quarter];
    uint4 pB0 = GATH(qB0), pB1 = GATH(qB1);
    float dA0 = (float)(qA0 & 0xFFFFu) * DINV, dA1 = (float)(qA1 & 0xFFFFu) * DINV;
    float dB0 = (float)(qB0 & 0xFFFFu) * DINV, dB1 = (float)(qB1 & 0xFFFFu) * DINV;
    L += 16;
    for (; L + 16 <= efull; L += 16){
      unsigned int nA0 = cd[L + quarter], nA1 = cd[L + 4 + quarter];
      AGG_PROC(pA0, dA0); AGG_PROC(pA1, dA1);
      pA0 = GATH(nA0); pA1 = GATH(nA1);
      dA0 = (float)(nA0 & 0xFFFFu) * DINV; dA1 = (float)(nA1 & 0xFFFFu) * DINV;
      unsigned int nB0 = cd[L + 8 + quarter], nB1 = cd[L + 12 + quarter];
      AGG_PROC(pB0, dB0); AGG_PROC(pB1, dB1);
      pB0 = GATH(nB0); pB1 = GATH(nB1);
      dB0 = (float)(nB0 & 0xFFFFu) * DINV; dB1 = (float)(nB1 & 0xFFFFu) * DINV;
    }
    // drain
    AGG_PROC(pA0, dA0); AGG_PROC(pA1, dA1);
    AGG_PROC(pB0, dB0); AGG_PROC(pB1, dB1);
  }
  for (; L + 8 <= efull; L += 8){
    unsigned int q0 = cd[L + quarter], q1 = cd[L + 4 + quarter];
    uint4 p0 = GATH(q0), p1 = GATH(q1);
    float d0 = (float)(q0 & 0xFFFFu) * DINV, d1 = (float)(q1 & 0xFFFFu) * DINV;
    AGG_PROC(p0, d0); AGG_PROC(p1, d1);
  }
  for (int j = efull; j < e; j += 4){
    int myj = j + quarter;
    if (myj < e){
      unsigned int q = cd[myj];
      uint4 p = GATH(q);
      float dd = (float)(q & 0xFFFFu) * DINV;
      AGG_PROC(p, dd);
    }
  }
  float4 av0 = *(const float4*)(a + fl);
  float4 av1 = *(const float4*)(a + fl + 4);
  float4 cv0 = *(const float4*)(c + fl);
  float4 cv1 = *(const float4*)(c + fl + 4);
  float r[8];
  r[0] = av0.x * s1[0] + cv0.x * s0[0];
  r[1] = av0.y * s1[1] + cv0.y * s0[1];
  r[2] = av0.z * s1[2] + cv0.z * s0[2];
  r[3] = av0.w * s1[3] + cv0.w * s0[3];
  r[4] = av1.x * s1[4] + cv1.x * s0[4];
  r[5] = av1.y * s1[5] + cv1.y * s0[5];
  r[6] = av1.z * s1[6] + cv1.z * s0[6];
  r[7] = av1.w * s1[7] + cv1.w * s0[7];
  #pragma unroll
  for (int k = 0; k < 8; ++k){
    r[k] += __shfl_down(r[k], 32, 64);
    r[k] += __shfl_down(r[k], 16, 64);
  }
  if (quarter == 0){
    uint4 st;
    st.x = (unsigned int)f2bf(r[0]) | ((unsigned int)f2bf(r[1]) << 16);
    st.y = (unsigned int)f2bf(r[2]) | ((unsigned int)f2bf(r[3]) << 16);
    st.z = (unsigned int)f2bf(r[4]) | ((unsigned int)f2bf(r[5]) << 16);
    st.w = (unsigned int)f2bf(r[6]) | ((unsigned int)f2bf(r[7]) << 16);
    *(uint4*)(aggHi + ((size_t)node << 7) + fl) = st;
  }
}

// ---------------- fused GEMM pair, column-split waves (r9, verified) ----------
__global__ __launch_bounds__(256, 2)
void k_fpair(const ushortT* __restrict__ agg, const ushortT* __restrict__ WoT,
             const float* __restrict__ bo, const ushortT* __restrict__ WnT,
             ushortT* __restrict__ outH, int N, int segTiles){
  __shared__ ushortT vt[2][32 * TSTR];
  int tid = threadIdx.x;
  int wave = tid >> 6, lane = tid & 63;
  int pairI = wave >> 1, half = wave & 1;
  int m = lane & 15, quad = lane >> 4;
  int ntiles = (N + 15) >> 4;
  int xcd = blockIdx.x & (NXCD - 1);
  int idx = blockIdx.x >> 3;
  int wjIdx = idx * 2 + pairI;
  int segWJ = segTiles >> 1;
  int t0 = xcd * segTiles + wjIdx * 2;
  bool act = (wjIdx < segWJ) && (t0 < ntiles);
  ushortT* vw = vt[pairI];

  bf16x8 av[2][4];
  if (act){
    #pragma unroll
    for (int rt = 0; rt < 2; ++rt){
      int row = (t0 + rt) * 16 + m; if (row >= N) row = N - 1;
      #pragma unroll
      for (int kk = 0; kk < 4; ++kk)
        av[rt][kk] = *(const bf16x8*)(agg + ((size_t)row << 7) + kk*32 + quad*8);
    }
    #pragma unroll
    for (int cti = 0; cti < 4; ++cti){
      int ncol = (half * 4 + cti) * 16 + m;
      const ushortT* bp = WoT + ((size_t)ncol << 7) + quad*8;
      bf16x8 bb[4];
      #pragma unroll
      for (int kk = 0; kk < 4; ++kk) bb[kk] = *(const bf16x8*)(bp + kk*32);
      float bbias = bo[ncol];
      #pragma unroll
      for (int rt = 0; rt < 2; ++rt){
        f32x4 d = mfma4r(av[rt], bb);
        #pragma unroll
        for (int r = 0; r < 4; ++r)
          vw[(rt*16 + quad*4 + r) * TSTR + ncol] = f2bf(ssp(d[r] + bbias));
      }
    }
  }
  __syncthreads();
  if (act){
    bf16x8 a2[2][4];
    #pragma unroll
    for (int rt = 0; rt < 2; ++rt){
      #pragma unroll
      for (int kk = 0; kk < 4; ++kk)
        a2[rt][kk] = *(const bf16x8*)(&vw[(rt*16 + m) * TSTR + kk*32 + quad*8]);
    }
    #pragma unroll
    for (int cti = 0; cti < 4; ++cti){
      int ncol = (half * 4 + cti) * 16 + m;
      const ushortT* bp = WnT + ((size_t)ncol << 7) + quad*8;
      bf16x8 bb[4];
      #pragma unroll
      for (int kk = 0; kk < 4; ++kk) bb[kk] = *(const bf16x8*)(bp + kk*32);
      #pragma unroll
      for (int rt = 0; rt < 2; ++rt){
        f32x4 d = mfma4r(a2[rt], bb);
        #pragma unroll
        for (int r = 0; r < 4; ++r){
          int orow = (t0 + rt) * 16 + quad*4 + r;
          if (orow < N) outH[((size_t)orow << 7) + ncol] = f2bf(d[r]);
        }
      }
    }
  }
}

// ------ last layer: column-split + fused group-sum, run-compacted atomics -----
// (r15 verified: segmented shfl-scan over sorted batch, run-tail lanes only
// -> ~3K atomics, contention gone.)
__global__ __launch_bounds__(256, 2)
void k_gfinal(const ushortT* __restrict__ agg, const ushortT* __restrict__ WoT,
              const float* __restrict__ bo, const ushortT* __restrict__ W1T,
              const float* __restrict__ b1, const float* __restrict__ W2,
              const float* __restrict__ b2, const int* __restrict__ batch,
              float* __restrict__ out, int N, int segTiles){
  __shared__ ushortT vt[2][32 * TSTR];
  __shared__ float part[2][2][32];
  int tid = threadIdx.x;
  int wave = tid >> 6, lane = tid & 63;
  int pairI = wave >> 1, half = wave & 1;
  int m = lane & 15, quad = lane >> 4;
  int ntiles = (N + 15) >> 4;
  int xcd = blockIdx.x & (NXCD - 1);
  int idx = blockIdx.x >> 3;
  int wjIdx = idx * 2 + pairI;
  int segWJ = segTiles >> 1;
  int t0 = xcd * segTiles + wjIdx * 2;
  bool act = (wjIdx < segWJ) && (t0 < ntiles);
  ushortT* vw = vt[pairI];

  if (act){
    bf16x8 av[2][4];
    #pragma unroll
    for (int rt = 0; rt < 2; ++rt){
      int row = (t0 + rt) * 16 + m; if (row >= N) row = N - 1;
      #pragma unroll
      for (int kk = 0; kk < 4; ++kk)
        av[rt][kk] = *(const bf16x8*)(agg + ((size_t)row << 7) + kk*32 + quad*8);
    }
    #pragma unroll
    for (int cti = 0; cti < 4; ++cti){
      int ncol = (half * 4 + cti) * 16 + m;
      const ushortT* bp = WoT + ((size_t)ncol << 7) + quad*8;
      bf16x8 bb[4];
      #pragma unroll
      for (int kk = 0; kk < 4; ++kk) bb[kk] = *(const bf16x8*)(bp + kk*32);
      float bbias = bo[ncol];
      #pragma unroll
      for (int rt = 0; rt < 2; ++rt){
        f32x4 d = mfma4r(av[rt], bb);
        #pragma unroll
        for (int r = 0; r < 4; ++r)
          vw[(rt*16 + quad*4 + r) * TSTR + ncol] = f2bf(ssp(d[r] + bbias));
      }
    }
  }
  __syncthreads();
  if (act){
    bf16x8 a2[2][4];
    #pragma unroll
    for (int rt = 0; rt < 2; ++rt){
      #pragma unroll
      for (int kk = 0; kk < 4; ++kk)
        a2[rt][kk] = *(const bf16x8*)(&vw[(rt*16 + m) * TSTR + kk*32 + quad*8]);
    }
    float acc[2][4] = {{0.f,0.f,0.f,0.f},{0.f,0.f,0.f,0.f}};
    #pragma unroll
    for (int cti = 0; cti < 2; ++cti){
      int ncol = (half * 2 + cti) * 16 + m;       // W1T: 64 cols total
      const ushortT* bp = W1T + ((size_t)ncol << 7) + quad*8;
      bf16x8 bb[4];
      #pragma unroll
      for (int kk = 0; kk < 4; ++kk) bb[kk] = *(const bf16x8*)(bp + kk*32);
      float bb1 = b1[ncol];
      float w2  = W2[ncol];
      #pragma unroll
      for (int rt = 0; rt < 2; ++rt){
        f32x4 d = mfma4r(a2[rt], bb);
        #pragma unroll
        for (int r = 0; r < 4; ++r)
          acc[rt][r] += ssp(d[r] + bb1) * w2;
      }
    }
    #pragma unroll
    for (int rt = 0; rt < 2; ++rt){
      #pragma unroll
      for (int r = 0; r < 4; ++r){
        float v = acc[rt][r];
        v += __shfl_xor(v, 1, 64);
        v += __shfl_xor(v, 2, 64);
        v += __shfl_xor(v, 4, 64);
        v += __shfl_xor(v, 8, 64);
        if (m == 0) part[pairI][half][rt*16 + quad*4 + r] = v;
      }
    }
  }
  __syncthreads();
  if (tid < 64){
    int p = tid >> 5, row = tid & 31;
    int wj = idx * 2 + p;
    int tt = xcd * segTiles + wj * 2;
    bool valid = (wj < segWJ) && (tt < ntiles);
    int orow = valid ? (tt * 16 + row) : 0;
    valid = valid && (orow < N);
    float v = 0.f; int g = -1;
    if (valid){
      v = part[p][0][row] + part[p][1][row] + b2[0];
      g = batch[orow];
    }
    // segmented inclusive scan over each 32-lane half (sorted batch => runs)
    #pragma unroll
    for (int off = 1; off < 32; off <<= 1){
      int src = tid - off; if (src < 0) src = 0;
      float ov = __shfl(v, src, 64);
      int   og = __shfl(g, src, 64);
      if (row >= off && og == g) v += ov;
    }
    if (valid){
      bool tail = (row == 31) || (orow == N - 1);
      if (!tail) tail = (batch[orow + 1] != g);
      if (tail) atomicAdd(&out[g], v);   // only run tails hit memory
    }
  }
}

extern "C" void kernel_launch(void* const* d_in, const int* in_sizes, int n_in,
                              void* d_out, int out_size, void* d_ws, size_t ws_size,
                              hipStream_t stream){
  const int N = in_sizes[0];
  const int E = in_sizes[3] / 2;
  const int G = out_size;

  const int*   z     = (const int*)d_in[0];
  const float* pos   = (const float*)d_in[1];
  const int*   batch = (const int*)d_in[2];
  const int*   eidx  = (const int*)d_in[3];
  const int*   erow  = eidx;
  const int*   ecol  = eidx + E;
  const float* emb   = (const float*)d_in[4];
  const float* dW    = (const float*)d_in[5];
  const float* db    = (const float*)d_in[6];
  const float* Wn    = (const float*)d_in[7];
  const float* We    = (const float*)d_in[8];
  const float* be    = (const float*)d_in[9];
  const float* Wo    = (const float*)d_in[10];
  const float* bo    = (const float*)d_in[11];
  const float* W1    = (const float*)d_in[12];
  const float* b1    = (const float*)d_in[13];
  const float* W2    = (const float*)d_in[14];
  const float* b2    = (const float*)d_in[15];

  char* ws = (char*)d_ws;
  size_t off = 0;
  auto alloc = [&](size_t bytes) -> char* {
    char* p = ws + off;
    off = (off + bytes + 255) & ~(size_t)255;
    return p;
  };
  size_t hbytes = (size_t)N * HDIM * 2;
  size_t stgbytes = (size_t)E * 8;
  int*          offsets  = (int*)         alloc((size_t)(N + 1) * 4);
  unsigned int* csr      = (unsigned int*)alloc((size_t)E * 4);
  ushortT*      h0       = (ushortT*)     alloc(hbytes);
  ushortT*      h1       = (ushortT*)     alloc(hbytes);    // aliased by hist during build
  ushortT*      agghi    = (ushortT*)     alloc(hbytes);
  ushortT*      stgbuf   = (ushortT*)     alloc(stgbytes);  // CSR staging records
  ushortT*      emb2     = (ushortT*)     alloc((size_t)100 * HDIM * 2);
  ushortT*      WnT      = (ushortT*)     alloc((size_t)NLAYER * HDIM * HDIM * 2);
  ushortT*      WoT      = (ushortT*)     alloc((size_t)NLAYER * HDIM * HDIM * 2);
  ushortT*      W1T      = (ushortT*)     alloc((size_t)64 * HDIM * 2);
  float*        a        = (float*)       alloc((size_t)NLAYER * HDIM * 4);
  float*        c        = (float*)       alloc((size_t)NLAYER * HDIM * 4);

  int*   hist       = (int*)h1;                 // NSTRIPE*512 ints = 1 MB
  int*   colTotal   = hist + NSTRIPE * 512;     // 512 ints
  uint2* stg        = (uint2*)stgbuf;           // E * 8 B

  int shift = 7;
  while ((((N - 1) >> shift) + 1) > 512) ++shift;
  int NB = ((N - 1) >> shift) + 1;
  int estripe = (E + NSTRIPE - 1) / NSTRIPE;

  int B0 = (100 * HDIM + 255) / 256;
  int B2 = (NLAYER * HDIM * HDIM / 8 + 255) / 256;
  int B4 = (NLAYER * HDIM + 255) / 256;
  int B7 = (64 * HDIM / 8 + 255) / 256;
  int B1h = (N * HDIM / 8 + 255) / 256;

  k_setup<<<B0 + 2*B2 + B4 + B7 + NSTRIPE, 256, 0, stream>>>(
      emb, emb2, Wn, WnT, Wo, WoT,
      dW, db, We, be, a, c, W1, W1T,
      erow, hist, (float*)d_out,
      N, G, E, estripe, NB, shift, B0, B2, B4, B7);

  k_colscan<<<NB + B1h, 256, 0, stream>>>(hist, colTotal, z, emb2, h0, N, NB);
  k_scatter<<<NSTRIPE, 256, 0, stream>>>(erow, ecol, pos, hist, colTotal,
                                         stg, E, NB, shift, estripe);
  k_place  <<<NB,      256, 0, stream>>>(stg, colTotal, offsets, csr, N, NB, shift, E);

  int ntiles = (N + 15) >> 4;
  int segTiles = (((ntiles + NXCD - 1) / NXCD) + 1) & ~1;   // even tiles/XCD
  int segNodes = segTiles * 16;
  int segWJ = segTiles >> 1;
  int aggGrid  = NXCD * ((segNodes + 3) / 4);
  int gGrid    = NXCD * ((segWJ + 1) / 2);

  for (int l = 0; l < NLAYER; ++l){
    size_t wo = (size_t)l * HDIM * HDIM;
    const ushortT* hin  = (l & 1) ? h1 : h0;
    ushortT*       hout = (l & 1) ? h0 : h1;
    k_agg2<<<aggGrid, 256, 0, stream>>>(hin, offsets, csr,
                                        a + l * HDIM, c + l * HDIM, agghi, N, segNodes);
    if (l < NLAYER - 1){
      size_t wn = (size_t)(l + 1) * HDIM * HDIM;
      k_fpair<<<gGrid, 256, 0, stream>>>(agghi, WoT + wo, bo + (size_t)l * HDIM,
                                         WnT + wn, hout, N, segTiles);
    } else {
      k_gfinal<<<gGrid, 256, 0, stream>>>(agghi, WoT + wo, bo + (size_t)l * HDIM,
                                          W1T, b1, W2, b2, batch,
                                          (float*)d_out, N, segTiles);
    }
  }
}